// Round 8
// baseline (1465.296 us; speedup 1.0000x reference)
//
#include <hip/hip_runtime.h>
#include <math.h>

#define BATCH 64
#define LSAMP 524288
#define KLEN 1024
#define HOP 512
#define CBIN 513
#define TWIN 1027
#define BCT (64LL * 513 * 1027)   // 33718464

typedef unsigned int uint32;
using short8   = __attribute__((ext_vector_type(8))) short;
using half8    = __attribute__((ext_vector_type(8))) _Float16;
using f32x4    = __attribute__((ext_vector_type(4))) float;

// ---- workspace layout (ushort element offsets) ----
// A region: 290 steps x 512 lane-units x 8 f16 (288 real + 2 prefetch pad)
#define ASTEPS    288
#define A_USHORTS ((uint32)(ASTEPS + 2) * 4096u)   // 1,187,840
#define XPLANE    526336                            // 1024 pad + 524288 + 1024 pad
#define XF_OFF    A_USHORTS
#define LIST_OFF_U (XF_OFF + 64u * (uint32)XPLANE)  // 34,873,344
#define LIST_CAP  2000000u
#define WS_NEED   ((size_t)(LIST_OFF_U + 8u + 2u * LIST_CAP) * 2)  // ~77.7 MB

__device__ __forceinline__ unsigned short bfh(float v) {
    uint32 u = __float_as_uint(v);
    return (unsigned short)((u + 0x7fffu + ((u >> 16) & 1u)) >> 16);
}
__device__ __forceinline__ float bf2f(unsigned short h) {
    return __uint_as_float(((uint32)h) << 16);
}

// ---------------- counter init ----------------
__global__ void zero_cnt(unsigned short* ws) {
    ((uint32*)(ws + LIST_OFF_U))[0] = 0u;
}

// ---------------- pre-pass: fb -> per-(step,wave,mi) coalesced f16 A-fragments ----------------
// unit id = ((step*4 + wq)*2 + mi2)*64 + lane ; lane=(lm,lg): row=wq*16+lm, k=ks*32+lg*8
__global__ __launch_bounds__(256)
void split_fb(const float* __restrict__ fb, unsigned short* __restrict__ ws) {
    int id = blockIdx.x * 256 + threadIdx.x;
    if (id >= ASTEPS * 512) return;
    int lane = id & 63;
    int rest = id >> 6;
    int mi2 = rest & 1; rest >>= 1;
    int wq  = rest & 3;
    int step = rest >> 2;
    int ct = step >> 5, ks = step & 31;
    int lm = lane & 15, lg = lane >> 4;
    int row = wq * 16 + lm;                     // 0..63
    int c0 = (ct < 8) ? ct * 64 : 449;
    int c  = (mi2 == 0) ? (c0 + row) : (513 + c0 + row);
    int k  = ks * 32 + lg * 8;
    const float4* src = (const float4*)(fb + (size_t)c * KLEN + k);
    float4 a = src[0], bq = src[1];
    float vv[8] = {a.x, a.y, a.z, a.w, bq.x, bq.y, bq.z, bq.w};
    half8 hv;
#pragma unroll
    for (int j = 0; j < 8; ++j) hv[j] = (_Float16)vv[j];
    *(half8*)&ws[(size_t)id * 8] = hv;
}

// ---------------- pre-pass: x -> zero-padded f16 plane ----------------
__global__ __launch_bounds__(256)
void split_x(const float* __restrict__ x, unsigned short* __restrict__ ws) {
    long i = (long)blockIdx.x * 256 + threadIdx.x;
    if (i >= 64L * (XPLANE / 8)) return;
    int b = (int)(i / (XPLANE / 8));
    int j = (int)(i % (XPLANE / 8)) * 8;
    long sample = (long)j - 1024;
    float vv[8] = {0.f,0.f,0.f,0.f,0.f,0.f,0.f,0.f};
    if (sample >= 0 && sample < LSAMP) {
        const float4* s = (const float4*)(x + (size_t)b * LSAMP + sample);
        float4 a = s[0], c = s[1];
        vv[0]=a.x; vv[1]=a.y; vv[2]=a.z; vv[3]=a.w;
        vv[4]=c.x; vv[5]=c.y; vv[6]=c.z; vv[7]=c.w;
    }
    half8 hv;
#pragma unroll
    for (int jj = 0; jj < 8; ++jj) hv[jj] = (_Float16)vv[jj];
    *(half8*)&ws[(size_t)XF_OFF + (size_t)b * XPLANE + j] = hv;
}

// ---------------- main GEMM: barrier-free K-loop, X resident in LDS, A global->reg ----------------
// Block: 256 thr (4 waves). Wave wq owns re rows [wq*16,+16) AND im rows (same c-range).
// Tile: per block, all 9 ct x 128 rows x 64 windows; 288 steps, no __syncthreads in loop.
__global__ __launch_bounds__(256, 2)
void stft_gemm(unsigned short* __restrict__ ws, float* __restrict__ out) {
    __shared__ __align__(16) unsigned short xs[65 * 512];   // 66,560 B resident X

    const int tid  = threadIdx.x;
    const int lane = tid & 63;
    const int wq   = tid >> 6;
    const int lm   = lane & 15;
    const int lg   = lane >> 4;

    const int ng = blockIdx.x % 17;
    const int b  = blockIdx.x / 17;
    const int N0 = ng * 64;

    // ---- fill resident X: 65 half-rows x 512 f16, unit-swizzled by (row&7) ----
    const unsigned short* xplane = ws + XF_OFF + (size_t)b * XPLANE;
    for (int uf = tid; uf < 65 * 64; uf += 256) {
        int j = uf >> 6, u = uf & 63;
        uint32 pidx = (uint32)(N0 + j) * 512u + (uint32)u * 8u;
        uint4 v = make_uint4(0u, 0u, 0u, 0u);
        if (pidx + 8u <= (uint32)XPLANE) v = *(const uint4*)&xplane[pidx];
        *(uint4*)&xs[j * 512 + ((u ^ (j & 7)) * 8)] = v;
    }
    __syncthreads();   // the ONLY barrier

    const unsigned short* Aw = ws;
    const uint32 abase0 = (uint32)(wq * 2 + 0) * 512u + (uint32)lane * 8u;
    const uint32 abase1 = (uint32)(wq * 2 + 1) * 512u + (uint32)lane * 8u;

    // prime 2-step register pipeline
    half8 a0r = *(const half8*)&Aw[abase0];
    half8 a0i = *(const half8*)&Aw[abase1];
    half8 a1r = *(const half8*)&Aw[4096u + abase0];
    half8 a1i = *(const half8*)&Aw[4096u + abase1];

    uint32* cntr = (uint32*)(ws + LIST_OFF_U);
    uint32* list = cntr + 4;
    const float pi_f = 3.14159265f;

    for (int ct = 0; ct < 9; ++ct) {
        const int c0 = (ct < 8) ? ct * 64 : 449;
        f32x4 acc[2][4];
#pragma unroll
        for (int ni = 0; ni < 4; ++ni) { acc[0][ni] = (f32x4)0.f; acc[1][ni] = (f32x4)0.f; }

#pragma unroll
        for (int ks = 0; ks < 32; ks += 2) {
            const int step = ct * 32 + ks;
            {   // even step: consume a0*, prefetch step+2
                const int bh = (ks >> 4) & 1;
                const int ub = (ks & 15) * 4;
#pragma unroll
                for (int ni = 0; ni < 4; ++ni) {
                    int j  = ni * 16 + lm + bh;
                    int pu = (ub + lg) ^ (j & 7);
                    half8 bf = *(const half8*)&xs[j * 512 + pu * 8];
                    acc[0][ni] = __builtin_amdgcn_mfma_f32_16x16x32_f16(a0r, bf, acc[0][ni], 0, 0, 0);
                    acc[1][ni] = __builtin_amdgcn_mfma_f32_16x16x32_f16(a0i, bf, acc[1][ni], 0, 0, 0);
                }
                const uint32 ao = (uint32)(step + 2) * 4096u;
                a0r = *(const half8*)&Aw[ao + abase0];
                a0i = *(const half8*)&Aw[ao + abase1];
            }
            {   // odd step: consume a1*, prefetch step+3
                const int k1 = ks + 1;
                const int bh = (k1 >> 4) & 1;
                const int ub = (k1 & 15) * 4;
#pragma unroll
                for (int ni = 0; ni < 4; ++ni) {
                    int j  = ni * 16 + lm + bh;
                    int pu = (ub + lg) ^ (j & 7);
                    half8 bf = *(const half8*)&xs[j * 512 + pu * 8];
                    acc[0][ni] = __builtin_amdgcn_mfma_f32_16x16x32_f16(a1r, bf, acc[0][ni], 0, 0, 0);
                    acc[1][ni] = __builtin_amdgcn_mfma_f32_16x16x32_f16(a1i, bf, acc[1][ni], 0, 0, 0);
                }
                const uint32 ao = (uint32)(step + 3) * 4096u;
                a1r = *(const half8*)&Aw[ao + abase0];
                a1i = *(const half8*)&Aw[ao + abase1];
            }
        }

        // ---- epilogue for this ct: re/im pairing is in-register; flag risky points ----
#pragma unroll
        for (int ni = 0; ni < 4; ++ni) {
#pragma unroll
            for (int r = 0; r < 4; ++r) {
                float re = acc[0][ni][r];
                float im = acc[1][ni][r];
                int c = c0 + wq * 16 + lg * 4 + r;
                int n = N0 + ni * 16 + lm;
                bool risky = false;
                size_t ob = 0;
                if (n < TWIN) {
                    float m  = sqrtf(fmaf(re, re, fmaf(im, im, 1e-10f)));
                    float pv = atan2f(im, re);
                    ob = ((size_t)b * CBIN + c) * TWIN + n;
                    out[ob]       = m;
                    out[BCT + ob] = pv;
                    bool edge = (n == 0) | (n == 1026);
                    bool axis = (c == 0) | (c == 512);
                    risky = !edge && ((m < 0.06f) ||
                                      (!axis && (pi_f - fabsf(pv)) * m < 0.08f));
                }
                unsigned long long mask = __ballot(risky);
                if (mask) {
                    int leader = __ffsll(mask) - 1;
                    uint32 bslot = 0;
                    if (lane == leader) bslot = atomicAdd(cntr, (uint32)__popcll(mask));
                    bslot = (uint32)__shfl((int)bslot, leader);
                    if (risky) {
                        uint32 slot = bslot + (uint32)__popcll(mask & ((1ULL << lane) - 1ULL));
                        if (slot < LIST_CAP) list[slot] = (uint32)ob;
                    }
                }
            }
        }
    }
}

// ---------------- axis rows c in {0,512}: full fp32 recompute (f16 flushed 1e-13 basis) ----
__global__ __launch_bounds__(256)
void stft_axis(const float* __restrict__ x, const float* __restrict__ fb,
               float* __restrict__ out) {
    const int gw   = (int)((blockIdx.x * 256 + threadIdx.x) >> 6);
    const int lane = threadIdx.x & 63;
    if (gw >= BATCH * TWIN) return;
    const int b = gw / TWIN;
    const int t = gw % TWIN;
    const long s = (long)t * HOP - KLEN;
    const float* xb  = x + (size_t)b * LSAMP;
    const float* fr0 = fb;
    const float* fi0 = fb + (size_t)513 * KLEN;
    const float* fr5 = fb + (size_t)512 * KLEN;
    const float* fi5 = fb + (size_t)1025 * KLEN;

    float re0 = 0.f, im0 = 0.f, re5 = 0.f, im5 = 0.f;
#pragma unroll 4
    for (int k = lane; k < KLEN; k += 64) {
        long gg = s + k;
        float xv = (gg >= 0 && gg < LSAMP) ? xb[gg] : 0.f;
        re0 = fmaf(xv, fr0[k], re0); im0 = fmaf(xv, fi0[k], im0);
        re5 = fmaf(xv, fr5[k], re5); im5 = fmaf(xv, fi5[k], im5);
    }
#pragma unroll
    for (int off = 32; off > 0; off >>= 1) {
        re0 += __shfl_down(re0, off); im0 += __shfl_down(im0, off);
        re5 += __shfl_down(re5, off); im5 += __shfl_down(im5, off);
    }
    if (lane == 0) {
        size_t b0 = ((size_t)b * CBIN + 0) * TWIN + t;
        out[b0]       = sqrtf(fmaf(re0, re0, fmaf(im0, im0, 1e-10f)));
        out[BCT + b0] = atan2f(im0, re0);
        size_t b5 = ((size_t)b * CBIN + 512) * TWIN + t;
        out[b5]       = sqrtf(fmaf(re5, re5, fmaf(im5, im5, 1e-10f)));
        out[BCT + b5] = atan2f(im5, re5);
    }
}

// ---------------- fp64 recompute over compacted risky list ----------------
__global__ __launch_bounds__(256)
void stft_fix2(const float* __restrict__ x, const float* __restrict__ fb,
               const unsigned short* __restrict__ ws, float* __restrict__ out) {
    const uint32* cntr = (const uint32*)(ws + LIST_OFF_U);
    const uint32* list = cntr + 4;
    uint32 count = *cntr;
    if (count > LIST_CAP) count = LIST_CAP;
    const int lane = threadIdx.x & 63;
    const uint32 gw = (uint32)((blockIdx.x * 256 + threadIdx.x) >> 6);
    const uint32 nw = gridDim.x * 4;
    for (uint32 i = gw; i < count; i += nw) {
        uint32 idx = list[i];
        uint32 rw = idx / 1027u;
        uint32 t  = idx - rw * 1027u;
        uint32 bb = rw / 513u;
        uint32 c  = rw - bb * 513u;
        const float* xb = x + (size_t)bb * LSAMP;
        const float* fr = fb + (size_t)c * KLEN;
        const float* fi = fb + (size_t)(513 + c) * KLEN;
        const long s = (long)t * HOP - KLEN;
        double re = 0.0, im = 0.0;
#pragma unroll 4
        for (int k = lane; k < KLEN; k += 64) {
            long gg = s + k;
            double xv = (gg >= 0 && gg < LSAMP) ? (double)xb[gg] : 0.0;
            re = fma((double)fr[k], xv, re);
            im = fma((double)fi[k], xv, im);
        }
#pragma unroll
        for (int off = 32; off > 0; off >>= 1) {
            re += __shfl_down(re, off);
            im += __shfl_down(im, off);
        }
        if (lane == 0) {
            out[idx]       = (float)sqrt(re * re + im * im + 1e-10);
            out[BCT + idx] = (float)atan2(im, re);
        }
    }
}

// ================= legacy fallback (R3/R5 verified path, used only if ws too small) =========
__global__ __launch_bounds__(256)
void stft_gemm_legacy(const float* __restrict__ x, const float* __restrict__ fb,
                      float* __restrict__ out) {
    __shared__ unsigned short sml[16384];
    unsigned short* AH = sml;
    unsigned short* AL = sml + 4096;
    unsigned short* BH = sml + 8192;
    unsigned short* BL = sml + 12288;

    const int tid  = threadIdx.x;
    const int lane = tid & 63;
    const int w    = tid >> 6;
    const int wm   = w >> 1;
    const int wn   = w & 1;
    const int lm   = lane & 15;
    const int lk   = (lane >> 4) * 8;

    const int ct = blockIdx.x;
    const int nt = blockIdx.y;
    const int b  = blockIdx.z;
    const int c0 = ct * 64;
    const int n0 = nt * 128;

    const float4* fbg = (const float4*)fb;
    const float*  xb  = x + (size_t)b * LSAMP;

    int srow[4], su[4], sfbrow[4];
    long sxbase0[4];
#pragma unroll
    for (int pp = 0; pp < 4; ++pp) {
        int id = pp * 256 + tid;
        int row = id >> 3, u = id & 7;
        srow[pp] = row; su[pp] = u;
        sfbrow[pp] = (row < 64) ? (c0 + row) : (513 + c0 + (row - 64));
        sxbase0[pp] = 512L * (n0 + row) + 4L * u - 1024L;
    }

    f32x4 acc[4][4];
#pragma unroll
    for (int i = 0; i < 4; ++i)
#pragma unroll
        for (int j = 0; j < 4; ++j) acc[i][j] = (f32x4)0.f;

    float4 pa[4], pb[4];
#pragma unroll
    for (int pp = 0; pp < 4; ++pp) {
        pa[pp] = fbg[(size_t)sfbrow[pp] * 256 + su[pp]];
        long base = sxbase0[pp];
        pb[pp] = (base >= 0 && base < LSAMP) ? *(const float4*)(xb + base)
                                             : make_float4(0.f, 0.f, 0.f, 0.f);
    }

    for (int ks = 0; ks < 32; ++ks) {
        __syncthreads();
#pragma unroll
        for (int pp = 0; pp < 4; ++pp) {
            int o = srow[pp] * 32 + su[pp] * 4;
            float4 va = pa[pp], vb = pb[pp];
            ushort4 h, l;
            h.x = bfh(va.x); l.x = bfh(va.x - bf2f(h.x));
            h.y = bfh(va.y); l.y = bfh(va.y - bf2f(h.y));
            h.z = bfh(va.z); l.z = bfh(va.z - bf2f(h.z));
            h.w = bfh(va.w); l.w = bfh(va.w - bf2f(h.w));
            *(ushort4*)&AH[o] = h; *(ushort4*)&AL[o] = l;
            h.x = bfh(vb.x); l.x = bfh(vb.x - bf2f(h.x));
            h.y = bfh(vb.y); l.y = bfh(vb.y - bf2f(h.y));
            h.z = bfh(vb.z); l.z = bfh(vb.z - bf2f(h.z));
            h.w = bfh(vb.w); l.w = bfh(vb.w - bf2f(h.w));
            *(ushort4*)&BH[o] = h; *(ushort4*)&BL[o] = l;
        }
        __syncthreads();

        if (ks < 31) {
            int k0n = (ks + 1) * 32;
#pragma unroll
            for (int pp = 0; pp < 4; ++pp) {
                pa[pp] = fbg[(size_t)sfbrow[pp] * 256 + (k0n >> 2) + su[pp]];
                long base = sxbase0[pp] + k0n;
                pb[pp] = (base >= 0 && base < LSAMP) ? *(const float4*)(xb + base)
                                                     : make_float4(0.f, 0.f, 0.f, 0.f);
            }
        }

        short8 ah[4], al[4], bh[4], bl[4];
#pragma unroll
        for (int mi = 0; mi < 4; ++mi) {
            int o = (wm * 64 + mi * 16 + lm) * 32 + lk;
            ah[mi] = *(const short8*)&AH[o];
            al[mi] = *(const short8*)&AL[o];
        }
#pragma unroll
        for (int ni = 0; ni < 4; ++ni) {
            int o = (wn * 64 + ni * 16 + lm) * 32 + lk;
            bh[ni] = *(const short8*)&BH[o];
            bl[ni] = *(const short8*)&BL[o];
        }
#pragma unroll
        for (int mi = 0; mi < 4; ++mi)
#pragma unroll
            for (int ni = 0; ni < 4; ++ni)
                acc[mi][ni] = __builtin_amdgcn_mfma_f32_16x16x32_bf16(ah[mi], bh[ni], acc[mi][ni], 0, 0, 0);
#pragma unroll
        for (int mi = 0; mi < 4; ++mi)
#pragma unroll
            for (int ni = 0; ni < 4; ++ni)
                acc[mi][ni] = __builtin_amdgcn_mfma_f32_16x16x32_bf16(ah[mi], bl[ni], acc[mi][ni], 0, 0, 0);
#pragma unroll
        for (int mi = 0; mi < 4; ++mi)
#pragma unroll
            for (int ni = 0; ni < 4; ++ni)
                acc[mi][ni] = __builtin_amdgcn_mfma_f32_16x16x32_bf16(al[mi], bh[ni], acc[mi][ni], 0, 0, 0);
    }

    float* epsRe = (float*)sml;
    float* epsIm = (float*)(sml + 8192);
#pragma unroll
    for (int h = 0; h < 2; ++h) {
        __syncthreads();
#pragma unroll
        for (int mi = 0; mi < 4; ++mi)
#pragma unroll
            for (int nj = 0; nj < 2; ++nj) {
                int ni = 2 * h + nj;
#pragma unroll
                for (int r = 0; r < 4; ++r) {
                    int cr   = mi * 16 + (lane >> 4) * 4 + r;
                    int nbuf = wn * 32 + nj * 16 + lm;
                    if (wm == 0) epsRe[cr * 64 + nbuf] = acc[mi][ni][r];
                    else         epsIm[cr * 64 + nbuf] = acc[mi][ni][r];
                }
            }
        __syncthreads();
#pragma unroll
        for (int qq = 0; qq < 16; ++qq) {
            int id   = qq * 256 + tid;
            int cr   = id >> 6;
            int nbuf = id & 63;
            int nr   = (nbuf >> 5) * 64 + h * 32 + (nbuf & 31);
            int n    = n0 + nr;
            if (n < TWIN) {
                float re = epsRe[cr * 64 + nbuf];
                float im = epsIm[cr * 64 + nbuf];
                size_t base = ((size_t)b * CBIN + (c0 + cr)) * TWIN + n;
                out[base]       = sqrtf(fmaf(re, re, fmaf(im, im, 1e-10f)));
                out[BCT + base] = atan2f(im, re);
            }
        }
    }
}

__global__ __launch_bounds__(256)
void stft_nyq(const float* __restrict__ x, const float* __restrict__ fb,
              float* __restrict__ out) {
    const int gw   = (int)((blockIdx.x * 256 + threadIdx.x) >> 6);
    const int lane = threadIdx.x & 63;
    if (gw >= BATCH * TWIN) return;
    const int b = gw / TWIN;
    const int t = gw % TWIN;
    const long s = (long)t * HOP - KLEN;
    const float* xb = x + (size_t)b * LSAMP;
    const float* frow  = fb + (size_t)512 * KLEN;
    const float* firow = fb + (size_t)1025 * KLEN;

    float re = 0.f, im = 0.f;
    for (int k = lane; k < KLEN; k += 64) {
        long gg = s + k;
        float xv = (gg >= 0 && gg < LSAMP) ? xb[gg] : 0.f;
        re = fmaf(xv, frow[k], re);
        im = fmaf(xv, firow[k], im);
    }
#pragma unroll
    for (int off = 32; off > 0; off >>= 1) {
        re += __shfl_down(re, off);
        im += __shfl_down(im, off);
    }
    if (lane == 0) {
        size_t base = ((size_t)b * CBIN + 512) * TWIN + t;
        out[base]       = sqrtf(fmaf(re, re, fmaf(im, im, 1e-10f)));
        out[BCT + base] = atan2f(im, re);
    }
}

__global__ __launch_bounds__(256)
void stft_fix_legacy(const float* __restrict__ x, const float* __restrict__ fb,
                     float* __restrict__ out) {
    const int lane = threadIdx.x & 63;
    const uint32 nquad = (uint32)(BCT / 4);
    const uint32 nquad_pad = (nquad + 63u) & ~63u;
    const uint32 stride = gridDim.x * 256;
    for (uint32 gq = blockIdx.x * 256 + threadIdx.x; gq < nquad_pad; gq += stride) {
        const bool live = gq < nquad;
        float mm[4] = {1e9f, 1e9f, 1e9f, 1e9f};
        float pp[4] = {0.f, 0.f, 0.f, 0.f};
        if (live) {
            float4 mv = *(const float4*)&out[(size_t)gq * 4];
            float4 pv = *(const float4*)&out[BCT + (size_t)gq * 4];
            mm[0]=mv.x; mm[1]=mv.y; mm[2]=mv.z; mm[3]=mv.w;
            pp[0]=pv.x; pp[1]=pv.y; pp[2]=pv.z; pp[3]=pv.w;
        }
        bool cand = false;
#pragma unroll
        for (int j = 0; j < 4; ++j)
            cand |= (mm[j] < 2e-3f) || ((3.14159265f - fabsf(pp[j])) * mm[j] < 3e-3f);
        if (__ballot(cand) == 0ULL) continue;

        bool risky[4] = {false, false, false, false};
        if (live) {
            uint32 i0  = gq * 4u;
            uint32 row = i0 / 1027u;
            uint32 t0  = i0 - row * 1027u;
            uint32 cc0 = row % 513u;
#pragma unroll
            for (int j = 0; j < 4; ++j) {
                uint32 t = t0 + j, c = cc0;
                if (t >= 1027u) { t -= 1027u; c = (c == 512u) ? 0u : c + 1u; }
                bool edge = (t == 0u) | (t == 1026u);
                bool axis = (c == 0u) | (c == 512u);
                risky[j] = !edge && ((mm[j] < 2e-3f) ||
                                     (!axis && (3.14159265f - fabsf(pp[j])) * mm[j] < 3e-3f));
            }
        }
#pragma unroll
        for (int j = 0; j < 4; ++j) {
            unsigned long long mask = __ballot(risky[j]);
            while (mask) {
                int src = __ffsll(mask) - 1;
                mask &= mask - 1;
                uint32 idx = (gq - lane + (uint32)src) * 4u + (uint32)j;
                uint32 rw = idx / 1027u;
                uint32 t  = idx - rw * 1027u;
                uint32 bb = rw / 513u;
                uint32 c  = rw - bb * 513u;
                const float* xb = x + (size_t)bb * LSAMP;
                const float* fr = fb + (size_t)c * KLEN;
                const float* fi = fb + (size_t)(513 + c) * KLEN;
                const long s = (long)t * HOP - KLEN;
                double re = 0.0, im = 0.0;
                for (int k = lane; k < KLEN; k += 64) {
                    long gg = s + k;
                    double xv = (gg >= 0 && gg < LSAMP) ? (double)xb[gg] : 0.0;
                    re = fma((double)fr[k], xv, re);
                    im = fma((double)fi[k], xv, im);
                }
#pragma unroll
                for (int off = 32; off > 0; off >>= 1) {
                    re += __shfl_down(re, off);
                    im += __shfl_down(im, off);
                }
                if (lane == 0) {
                    out[idx]       = (float)sqrt(re * re + im * im + 1e-10);
                    out[BCT + idx] = (float)atan2(im, re);
                }
            }
        }
    }
}

extern "C" void kernel_launch(void* const* d_in, const int* in_sizes, int n_in,
                              void* d_out, int out_size, void* d_ws, size_t ws_size,
                              hipStream_t stream) {
    const float* x  = (const float*)d_in[0];
    const float* fb = (const float*)d_in[1];
    float* out = (float*)d_out;

    if (ws_size >= WS_NEED) {
        unsigned short* ws = (unsigned short*)d_ws;
        zero_cnt<<<1, 1, 0, stream>>>(ws);
        split_fb<<<(ASTEPS * 512 + 255) / 256, 256, 0, stream>>>(fb, ws);
        split_x<<<(64 * (XPLANE / 8) + 255) / 256, 256, 0, stream>>>(x, ws);
        stft_gemm<<<64 * 17, 256, 0, stream>>>(ws, out);
        stft_axis<<<(BATCH * TWIN * 64 + 255) / 256, 256, 0, stream>>>(x, fb, out);
        stft_fix2<<<1024, 256, 0, stream>>>(x, fb, ws, out);
    } else {
        dim3 grid(8, 9, BATCH);
        stft_gemm_legacy<<<grid, 256, 0, stream>>>(x, fb, out);
        int nwaves = BATCH * TWIN;
        int nblk = (nwaves * 64 + 255) / 256;
        stft_nyq<<<nblk, 256, 0, stream>>>(x, fb, out);
        stft_fix_legacy<<<2048, 256, 0, stream>>>(x, fb, out);
    }
}

// Round 9
// 821.745 us; speedup vs baseline: 1.7832x; 1.7832x over previous
//
#include <hip/hip_runtime.h>
#include <math.h>

#define BATCH 64
#define LSAMP 524288
#define KLEN 1024
#define HOP 512
#define CBIN 513
#define TWIN 1027
#define BCT (64LL * 513 * 1027)   // 33718464

typedef unsigned int uint32;
using short8   = __attribute__((ext_vector_type(8))) short;
using half8    = __attribute__((ext_vector_type(8))) _Float16;
using f32x4    = __attribute__((ext_vector_type(4))) float;

// ---- f16 workspace layout (ushort element offsets), BK=32 R5 tiling ----
#define FBT_SLOTS (9 * 32 * 512)                  // 147456 slots of 8 f16
#define XPLANE    526336                          // 1024 pad + 524288 + 1024 pad
#define XF_OFF    ((uint32)FBT_SLOTS * 8u)        // 1,179,648
#define LIST_OFF_U (XF_OFF + 64u * (uint32)XPLANE) // 34,865,152
#define LIST_CAP  2000000u
#define WS_NEED   ((size_t)(LIST_OFF_U + 8u + 2u * LIST_CAP) * 2)  // ~77.7 MB

__device__ __forceinline__ unsigned short bfh(float v) {
    uint32 u = __float_as_uint(v);
    return (unsigned short)((u + 0x7fffu + ((u >> 16) & 1u)) >> 16);
}
__device__ __forceinline__ float bf2f(unsigned short h) {
    return __uint_as_float(((uint32)h) << 16);
}
__device__ __forceinline__ void gld16(const void* g, void* l) {
    using GT = const __attribute__((address_space(1))) unsigned int;
    using LT = __attribute__((address_space(3))) unsigned int;
    __builtin_amdgcn_global_load_lds((GT*)g, (LT*)l, 16, 0, 0);
}

__global__ void zero_cnt(unsigned short* ws) {
    ((uint32*)(ws + LIST_OFF_U))[0] = 0u;
}

// ---------------- pre-pass: fb -> pre-swizzled f16 tiles (BK=32, verified R7 layout) ----------
__global__ __launch_bounds__(256)
void split_fb(const float* __restrict__ fb, unsigned short* __restrict__ ws) {
    int id = blockIdx.x * 256 + threadIdx.x;
    if (id >= FBT_SLOTS) return;
    int slot = id & 511;
    int tile = id >> 9;          // ct*32 + ks
    int ks = tile & 31;
    int ct = tile >> 5;
    int row = slot >> 2;                        // 0..127
    int lu  = (slot & 3) ^ ((row >> 1) & 3);
    int c0 = (ct < 8) ? ct * 64 : 449;
    int c = (row < 64) ? (c0 + row) : (513 + c0 + (row - 64));
    int k0 = ks * 32 + lu * 8;
    const float4* src = (const float4*)(fb + (size_t)c * KLEN + k0);
    float4 a = src[0], b = src[1];
    float vv[8] = {a.x, a.y, a.z, a.w, b.x, b.y, b.z, b.w};
    half8 hv;
#pragma unroll
    for (int j = 0; j < 8; ++j) hv[j] = (_Float16)vv[j];
    *(half8*)&ws[(size_t)id * 8] = hv;
}

// ---------------- pre-pass: x -> zero-padded f16 plane ----------------
__global__ __launch_bounds__(256)
void split_x(const float* __restrict__ x, unsigned short* __restrict__ ws) {
    long i = (long)blockIdx.x * 256 + threadIdx.x;
    if (i >= 64L * (XPLANE / 8)) return;
    int b = (int)(i / (XPLANE / 8));
    int j = (int)(i % (XPLANE / 8)) * 8;
    long sample = (long)j - 1024;
    float vv[8] = {0.f,0.f,0.f,0.f,0.f,0.f,0.f,0.f};
    if (sample >= 0 && sample < LSAMP) {
        const float4* s = (const float4*)(x + (size_t)b * LSAMP + sample);
        float4 a = s[0], c = s[1];
        vv[0]=a.x; vv[1]=a.y; vv[2]=a.z; vv[3]=a.w;
        vv[4]=c.x; vv[5]=c.y; vv[6]=c.z; vv[7]=c.w;
    }
    half8 hv;
#pragma unroll
    for (int jj = 0; jj < 8; ++jj) hv[jj] = (_Float16)vv[jj];
    *(half8*)&ws[(size_t)XF_OFF + (size_t)b * XPLANE + j] = hv;
}

// ---------------- main GEMM: 4-deep ring, counted vmcnt, raw barriers, f16 ----------------
// Ring: 4 bufs x 16KB (A 8KB | B 8KB). Per wave per STAGE: 4 gld16.
// Loop: wait vmcnt(8) -> s_barrier -> STAGE(ks+3) -> ds_read -> setprio(1) MFMAx16 setprio(0).
__global__ __launch_bounds__(256, 2)
void stft_gemm(unsigned short* __restrict__ ws, float* __restrict__ out) {
    extern __shared__ unsigned short sm[];   // 65536 B

    const int tid  = threadIdx.x;
    const int lane = tid & 63;
    const int w    = tid >> 6;
    const int wm   = w >> 1;          // 0: re rows, 1: im rows
    const int wn   = w & 1;
    const int lm   = lane & 15;
    const int lg   = lane >> 4;
    const uint32 swz = (uint32)((lm >> 1) & 3);

    const int p   = blockIdx.x;
    const int xcd = p & 7;
    const int q   = p >> 3;
    const int ct  = q % 9;
    const int g   = (q / 9) * 8 + xcd;
    const int nt  = g % 9;
    const int b   = g / 9;
    const int c0  = (ct < 8) ? ct * 64 : 449;
    const int n0  = nt * 128;

    // fragment LDS offsets (verified layout, R7)
    uint32 aoff[4], boff[4];
#pragma unroll
    for (int mi = 0; mi < 4; ++mi)
        aoff[mi] = (uint32)(wm * 64 + mi * 16 + lm) * 32u + (uint32)(lg ^ (int)swz) * 8u;
#pragma unroll
    for (int ni = 0; ni < 4; ++ni)
        boff[ni] = 4096u + (uint32)(wn * 64 + ni * 16 + lm) * 32u + (uint32)(lg ^ (int)swz) * 8u;

    f32x4 acc[4][4];
#pragma unroll
    for (int i = 0; i < 4; ++i)
#pragma unroll
        for (int j = 0; j < 4; ++j) acc[i][j] = (f32x4)0.f;

    auto STAGE = [&](int d, int ks) {
        const uint32 atile = (uint32)(ct * 32 + ks) * 4096u;
        const uint32 dbase = (uint32)d * 8192u;
#pragma unroll
        for (int r = 0; r < 2; ++r) {
            const uint32 slot = (uint32)(w * 128 + r * 64 + lane);
            gld16(&ws[atile + slot * 8u], &sm[dbase + slot * 8u]);          // A
            const uint32 brow = slot >> 2;
            const uint32 lu   = (slot & 3u) ^ ((brow >> 1) & 3u);
            uint32 pidx = (uint32)(n0 + brow) * 512u + (uint32)ks * 32u + lu * 8u;
            if (pidx > (uint32)(XPLANE - 8)) pidx = (uint32)(XPLANE - 8);
            gld16(&ws[(size_t)XF_OFF + (size_t)b * XPLANE + pidx],
                  &sm[dbase + 4096u + slot * 8u]);                          // B
        }
    };

    // prologue: 3 STAGEs in flight
    STAGE(0, 0);
    STAGE(1, 1);
    STAGE(2, 2);

#pragma unroll 4
    for (int ks = 0; ks < 32; ++ks) {
        // wait for buf[ks&3]'s loads (ours), keep newer STAGEs in flight
        if (ks <= 29)      { asm volatile("s_waitcnt vmcnt(8)" ::: "memory"); }
        else if (ks == 30) { asm volatile("s_waitcnt vmcnt(4)" ::: "memory"); }
        else               { asm volatile("s_waitcnt vmcnt(0)" ::: "memory"); }
        __builtin_amdgcn_sched_barrier(0);
        __builtin_amdgcn_s_barrier();      // all waves' buf[ks&3] ready; all done reading buf[(ks-1)&3]
        __builtin_amdgcn_sched_barrier(0);

        if (ks + 3 < 32) STAGE((ks + 3) & 3, ks + 3);   // overwrites buf[(ks-1)&3], safe post-barrier

        const uint32 base = (uint32)(ks & 3) * 8192u;
        half8 ah[4];
#pragma unroll
        for (int mi = 0; mi < 4; ++mi)
            ah[mi] = *(const half8*)&sm[base + aoff[mi]];

        __builtin_amdgcn_s_setprio(1);
#pragma unroll
        for (int ni = 0; ni < 4; ++ni) {
            half8 bh = *(const half8*)&sm[base + boff[ni]];
#pragma unroll
            for (int mi = 0; mi < 4; ++mi)
                acc[mi][ni] = __builtin_amdgcn_mfma_f32_16x16x32_f16(ah[mi], bh, acc[mi][ni], 0, 0, 0);
        }
        __builtin_amdgcn_s_setprio(0);
    }

    __syncthreads();   // full drain before repurposing LDS

    // ---------------- epilogue: two n-halves, mag+phase, fused risky-flagging (verified) -------
    float* epsRe = (float*)sm;
    float* epsIm = ((float*)sm) + 64 * 66;
    uint32* cntr = (uint32*)(ws + LIST_OFF_U);
    uint32* list = cntr + 4;
    const float pi_f = 3.14159265f;

#pragma unroll
    for (int h = 0; h < 2; ++h) {
        __syncthreads();
#pragma unroll
        for (int mi = 0; mi < 4; ++mi)
#pragma unroll
            for (int nj = 0; nj < 2; ++nj) {
                int ni = 2 * h + nj;
#pragma unroll
                for (int r = 0; r < 4; ++r) {
                    int cr   = mi * 16 + lg * 4 + r;
                    int nbuf = wn * 32 + nj * 16 + lm;
                    if (wm == 0) epsRe[cr * 66 + nbuf] = acc[mi][ni][r];
                    else         epsIm[cr * 66 + nbuf] = acc[mi][ni][r];
                }
            }
        __syncthreads();
#pragma unroll 4
        for (int qq = 0; qq < 16; ++qq) {
            int id   = qq * 256 + tid;
            int cr   = id >> 6;
            int nbuf = id & 63;
            int nr   = (nbuf >> 5) * 64 + h * 32 + (nbuf & 31);
            int n    = n0 + nr;
            bool risky = false;
            size_t ob = 0;
            if (n < TWIN) {
                float re = epsRe[cr * 66 + nbuf];
                float im = epsIm[cr * 66 + nbuf];
                int c = c0 + cr;
                float m  = sqrtf(fmaf(re, re, fmaf(im, im, 1e-10f)));
                float pv = atan2f(im, re);
                ob = ((size_t)b * CBIN + c) * TWIN + n;
                out[ob]       = m;
                out[BCT + ob] = pv;
                bool edge = (n == 0) | (n == 1026);
                bool axis = (c == 0) | (c == 512);
                risky = !edge && ((m < 0.06f) ||
                                  (!axis && (pi_f - fabsf(pv)) * m < 0.08f));
            }
            unsigned long long mask = __ballot(risky);
            if (mask) {
                int leader = __ffsll(mask) - 1;
                uint32 bslot = 0;
                if (lane == leader) bslot = atomicAdd(cntr, (uint32)__popcll(mask));
                bslot = (uint32)__shfl((int)bslot, leader);
                if (risky) {
                    uint32 slot = bslot + (uint32)__popcll(mask & ((1ULL << lane) - 1ULL));
                    if (slot < LIST_CAP) list[slot] = (uint32)ob;
                }
            }
        }
    }
}

// ---------------- axis rows c in {0,512}: full fp32 recompute ----------------
__global__ __launch_bounds__(256)
void stft_axis(const float* __restrict__ x, const float* __restrict__ fb,
               float* __restrict__ out) {
    const int gw   = (int)((blockIdx.x * 256 + threadIdx.x) >> 6);
    const int lane = threadIdx.x & 63;
    if (gw >= BATCH * TWIN) return;
    const int b = gw / TWIN;
    const int t = gw % TWIN;
    const long s = (long)t * HOP - KLEN;
    const float* xb  = x + (size_t)b * LSAMP;
    const float* fr0 = fb;
    const float* fi0 = fb + (size_t)513 * KLEN;
    const float* fr5 = fb + (size_t)512 * KLEN;
    const float* fi5 = fb + (size_t)1025 * KLEN;

    float re0 = 0.f, im0 = 0.f, re5 = 0.f, im5 = 0.f;
#pragma unroll 4
    for (int k = lane; k < KLEN; k += 64) {
        long gg = s + k;
        float xv = (gg >= 0 && gg < LSAMP) ? xb[gg] : 0.f;
        re0 = fmaf(xv, fr0[k], re0); im0 = fmaf(xv, fi0[k], im0);
        re5 = fmaf(xv, fr5[k], re5); im5 = fmaf(xv, fi5[k], im5);
    }
#pragma unroll
    for (int off = 32; off > 0; off >>= 1) {
        re0 += __shfl_down(re0, off); im0 += __shfl_down(im0, off);
        re5 += __shfl_down(re5, off); im5 += __shfl_down(im5, off);
    }
    if (lane == 0) {
        size_t b0 = ((size_t)b * CBIN + 0) * TWIN + t;
        out[b0]       = sqrtf(fmaf(re0, re0, fmaf(im0, im0, 1e-10f)));
        out[BCT + b0] = atan2f(im0, re0);
        size_t b5 = ((size_t)b * CBIN + 512) * TWIN + t;
        out[b5]       = sqrtf(fmaf(re5, re5, fmaf(im5, im5, 1e-10f)));
        out[BCT + b5] = atan2f(im5, re5);
    }
}

// ---------------- fp64 recompute over compacted risky list ----------------
__global__ __launch_bounds__(256)
void stft_fix2(const float* __restrict__ x, const float* __restrict__ fb,
               const unsigned short* __restrict__ ws, float* __restrict__ out) {
    const uint32* cntr = (const uint32*)(ws + LIST_OFF_U);
    const uint32* list = cntr + 4;
    uint32 count = *cntr;
    if (count > LIST_CAP) count = LIST_CAP;
    const int lane = threadIdx.x & 63;
    const uint32 gw = (uint32)((blockIdx.x * 256 + threadIdx.x) >> 6);
    const uint32 nw = gridDim.x * 4;
    for (uint32 i = gw; i < count; i += nw) {
        uint32 idx = list[i];
        uint32 rw = idx / 1027u;
        uint32 t  = idx - rw * 1027u;
        uint32 bb = rw / 513u;
        uint32 c  = rw - bb * 513u;
        const float* xb = x + (size_t)bb * LSAMP;
        const float* fr = fb + (size_t)c * KLEN;
        const float* fi = fb + (size_t)(513 + c) * KLEN;
        const long s = (long)t * HOP - KLEN;
        double re = 0.0, im = 0.0;
#pragma unroll 4
        for (int k = lane; k < KLEN; k += 64) {
            long gg = s + k;
            double xv = (gg >= 0 && gg < LSAMP) ? (double)xb[gg] : 0.0;
            re = fma((double)fr[k], xv, re);
            im = fma((double)fi[k], xv, im);
        }
#pragma unroll
        for (int off = 32; off > 0; off >>= 1) {
            re += __shfl_down(re, off);
            im += __shfl_down(im, off);
        }
        if (lane == 0) {
            out[idx]       = (float)sqrt(re * re + im * im + 1e-10);
            out[BCT + idx] = (float)atan2(im, re);
        }
    }
}

// ================= legacy fallback (verified R3/R5 path, only if ws too small) =================
__global__ __launch_bounds__(256)
void stft_gemm_legacy(const float* __restrict__ x, const float* __restrict__ fb,
                      float* __restrict__ out) {
    __shared__ unsigned short sml[16384];
    unsigned short* AH = sml;
    unsigned short* AL = sml + 4096;
    unsigned short* BH = sml + 8192;
    unsigned short* BL = sml + 12288;

    const int tid  = threadIdx.x;
    const int lane = tid & 63;
    const int w    = tid >> 6;
    const int wm   = w >> 1;
    const int wn   = w & 1;
    const int lm   = lane & 15;
    const int lk   = (lane >> 4) * 8;

    const int ct = blockIdx.x;
    const int nt = blockIdx.y;
    const int b  = blockIdx.z;
    const int c0 = ct * 64;
    const int n0 = nt * 128;

    const float4* fbg = (const float4*)fb;
    const float*  xb  = x + (size_t)b * LSAMP;

    int srow[4], su[4], sfbrow[4];
    long sxbase0[4];
#pragma unroll
    for (int pp = 0; pp < 4; ++pp) {
        int id = pp * 256 + tid;
        int row = id >> 3, u = id & 7;
        srow[pp] = row; su[pp] = u;
        sfbrow[pp] = (row < 64) ? (c0 + row) : (513 + c0 + (row - 64));
        sxbase0[pp] = 512L * (n0 + row) + 4L * u - 1024L;
    }

    f32x4 acc[4][4];
#pragma unroll
    for (int i = 0; i < 4; ++i)
#pragma unroll
        for (int j = 0; j < 4; ++j) acc[i][j] = (f32x4)0.f;

    float4 pa[4], pb[4];
#pragma unroll
    for (int pp = 0; pp < 4; ++pp) {
        pa[pp] = fbg[(size_t)sfbrow[pp] * 256 + su[pp]];
        long base = sxbase0[pp];
        pb[pp] = (base >= 0 && base < LSAMP) ? *(const float4*)(xb + base)
                                             : make_float4(0.f, 0.f, 0.f, 0.f);
    }

    for (int ks = 0; ks < 32; ++ks) {
        __syncthreads();
#pragma unroll
        for (int pp = 0; pp < 4; ++pp) {
            int o = srow[pp] * 32 + su[pp] * 4;
            float4 va = pa[pp], vb = pb[pp];
            ushort4 h, l;
            h.x = bfh(va.x); l.x = bfh(va.x - bf2f(h.x));
            h.y = bfh(va.y); l.y = bfh(va.y - bf2f(h.y));
            h.z = bfh(va.z); l.z = bfh(va.z - bf2f(h.z));
            h.w = bfh(va.w); l.w = bfh(va.w - bf2f(h.w));
            *(ushort4*)&AH[o] = h; *(ushort4*)&AL[o] = l;
            h.x = bfh(vb.x); l.x = bfh(vb.x - bf2f(h.x));
            h.y = bfh(vb.y); l.y = bfh(vb.y - bf2f(h.y));
            h.z = bfh(vb.z); l.z = bfh(vb.z - bf2f(h.z));
            h.w = bfh(vb.w); l.w = bfh(vb.w - bf2f(h.w));
            *(ushort4*)&BH[o] = h; *(ushort4*)&BL[o] = l;
        }
        __syncthreads();

        if (ks < 31) {
            int k0n = (ks + 1) * 32;
#pragma unroll
            for (int pp = 0; pp < 4; ++pp) {
                pa[pp] = fbg[(size_t)sfbrow[pp] * 256 + (k0n >> 2) + su[pp]];
                long base = sxbase0[pp] + k0n;
                pb[pp] = (base >= 0 && base < LSAMP) ? *(const float4*)(xb + base)
                                                     : make_float4(0.f, 0.f, 0.f, 0.f);
            }
        }

        short8 ah[4], al[4], bh[4], bl[4];
#pragma unroll
        for (int mi = 0; mi < 4; ++mi) {
            int o = (wm * 64 + mi * 16 + lm) * 32 + lk;
            ah[mi] = *(const short8*)&AH[o];
            al[mi] = *(const short8*)&AL[o];
        }
#pragma unroll
        for (int ni = 0; ni < 4; ++ni) {
            int o = (wn * 64 + ni * 16 + lm) * 32 + lk;
            bh[ni] = *(const short8*)&BH[o];
            bl[ni] = *(const short8*)&BL[o];
        }
#pragma unroll
        for (int mi = 0; mi < 4; ++mi)
#pragma unroll
            for (int ni = 0; ni < 4; ++ni)
                acc[mi][ni] = __builtin_amdgcn_mfma_f32_16x16x32_bf16(ah[mi], bh[ni], acc[mi][ni], 0, 0, 0);
#pragma unroll
        for (int mi = 0; mi < 4; ++mi)
#pragma unroll
            for (int ni = 0; ni < 4; ++ni)
                acc[mi][ni] = __builtin_amdgcn_mfma_f32_16x16x32_bf16(ah[mi], bl[ni], acc[mi][ni], 0, 0, 0);
#pragma unroll
        for (int mi = 0; mi < 4; ++mi)
#pragma unroll
            for (int ni = 0; ni < 4; ++ni)
                acc[mi][ni] = __builtin_amdgcn_mfma_f32_16x16x32_bf16(al[mi], bh[ni], acc[mi][ni], 0, 0, 0);
    }

    float* epsRe = (float*)sml;
    float* epsIm = (float*)(sml + 8192);
#pragma unroll
    for (int h = 0; h < 2; ++h) {
        __syncthreads();
#pragma unroll
        for (int mi = 0; mi < 4; ++mi)
#pragma unroll
            for (int nj = 0; nj < 2; ++nj) {
                int ni = 2 * h + nj;
#pragma unroll
                for (int r = 0; r < 4; ++r) {
                    int cr   = mi * 16 + (lane >> 4) * 4 + r;
                    int nbuf = wn * 32 + nj * 16 + lm;
                    if (wm == 0) epsRe[cr * 64 + nbuf] = acc[mi][ni][r];
                    else         epsIm[cr * 64 + nbuf] = acc[mi][ni][r];
                }
            }
        __syncthreads();
#pragma unroll
        for (int qq = 0; qq < 16; ++qq) {
            int id   = qq * 256 + tid;
            int cr   = id >> 6;
            int nbuf = id & 63;
            int nr   = (nbuf >> 5) * 64 + h * 32 + (nbuf & 31);
            int n    = n0 + nr;
            if (n < TWIN) {
                float re = epsRe[cr * 64 + nbuf];
                float im = epsIm[cr * 64 + nbuf];
                size_t base = ((size_t)b * CBIN + (c0 + cr)) * TWIN + n;
                out[base]       = sqrtf(fmaf(re, re, fmaf(im, im, 1e-10f)));
                out[BCT + base] = atan2f(im, re);
            }
        }
    }
}

__global__ __launch_bounds__(256)
void stft_nyq(const float* __restrict__ x, const float* __restrict__ fb,
              float* __restrict__ out) {
    const int gw   = (int)((blockIdx.x * 256 + threadIdx.x) >> 6);
    const int lane = threadIdx.x & 63;
    if (gw >= BATCH * TWIN) return;
    const int b = gw / TWIN;
    const int t = gw % TWIN;
    const long s = (long)t * HOP - KLEN;
    const float* xb = x + (size_t)b * LSAMP;
    const float* frow  = fb + (size_t)512 * KLEN;
    const float* firow = fb + (size_t)1025 * KLEN;

    float re = 0.f, im = 0.f;
    for (int k = lane; k < KLEN; k += 64) {
        long gg = s + k;
        float xv = (gg >= 0 && gg < LSAMP) ? xb[gg] : 0.f;
        re = fmaf(xv, frow[k], re);
        im = fmaf(xv, firow[k], im);
    }
#pragma unroll
    for (int off = 32; off > 0; off >>= 1) {
        re += __shfl_down(re, off);
        im += __shfl_down(im, off);
    }
    if (lane == 0) {
        size_t base = ((size_t)b * CBIN + 512) * TWIN + t;
        out[base]       = sqrtf(fmaf(re, re, fmaf(im, im, 1e-10f)));
        out[BCT + base] = atan2f(im, re);
    }
}

__global__ __launch_bounds__(256)
void stft_fix_legacy(const float* __restrict__ x, const float* __restrict__ fb,
                     float* __restrict__ out) {
    const int lane = threadIdx.x & 63;
    const uint32 nquad = (uint32)(BCT / 4);
    const uint32 nquad_pad = (nquad + 63u) & ~63u;
    const uint32 stride = gridDim.x * 256;
    for (uint32 gq = blockIdx.x * 256 + threadIdx.x; gq < nquad_pad; gq += stride) {
        const bool live = gq < nquad;
        float mm[4] = {1e9f, 1e9f, 1e9f, 1e9f};
        float pp[4] = {0.f, 0.f, 0.f, 0.f};
        if (live) {
            float4 mv = *(const float4*)&out[(size_t)gq * 4];
            float4 pv = *(const float4*)&out[BCT + (size_t)gq * 4];
            mm[0]=mv.x; mm[1]=mv.y; mm[2]=mv.z; mm[3]=mv.w;
            pp[0]=pv.x; pp[1]=pv.y; pp[2]=pv.z; pp[3]=pv.w;
        }
        bool cand = false;
#pragma unroll
        for (int j = 0; j < 4; ++j)
            cand |= (mm[j] < 2e-3f) || ((3.14159265f - fabsf(pp[j])) * mm[j] < 3e-3f);
        if (__ballot(cand) == 0ULL) continue;

        bool risky[4] = {false, false, false, false};
        if (live) {
            uint32 i0  = gq * 4u;
            uint32 row = i0 / 1027u;
            uint32 t0  = i0 - row * 1027u;
            uint32 cc0 = row % 513u;
#pragma unroll
            for (int j = 0; j < 4; ++j) {
                uint32 t = t0 + j, c = cc0;
                if (t >= 1027u) { t -= 1027u; c = (c == 512u) ? 0u : c + 1u; }
                bool edge = (t == 0u) | (t == 1026u);
                bool axis = (c == 0u) | (c == 512u);
                risky[j] = !edge && ((mm[j] < 2e-3f) ||
                                     (!axis && (3.14159265f - fabsf(pp[j])) * mm[j] < 3e-3f));
            }
        }
#pragma unroll
        for (int j = 0; j < 4; ++j) {
            unsigned long long mask = __ballot(risky[j]);
            while (mask) {
                int src = __ffsll(mask) - 1;
                mask &= mask - 1;
                uint32 idx = (gq - lane + (uint32)src) * 4u + (uint32)j;
                uint32 rw = idx / 1027u;
                uint32 t  = idx - rw * 1027u;
                uint32 bb = rw / 513u;
                uint32 c  = rw - bb * 513u;
                const float* xb = x + (size_t)bb * LSAMP;
                const float* fr = fb + (size_t)c * KLEN;
                const float* fi = fb + (size_t)(513 + c) * KLEN;
                const long s = (long)t * HOP - KLEN;
                double re = 0.0, im = 0.0;
                for (int k = lane; k < KLEN; k += 64) {
                    long gg = s + k;
                    double xv = (gg >= 0 && gg < LSAMP) ? (double)xb[gg] : 0.0;
                    re = fma((double)fr[k], xv, re);
                    im = fma((double)fi[k], xv, im);
                }
#pragma unroll
                for (int off = 32; off > 0; off >>= 1) {
                    re += __shfl_down(re, off);
                    im += __shfl_down(im, off);
                }
                if (lane == 0) {
                    out[idx]       = (float)sqrt(re * re + im * im + 1e-10);
                    out[BCT + idx] = (float)atan2(im, re);
                }
            }
        }
    }
}

extern "C" void kernel_launch(void* const* d_in, const int* in_sizes, int n_in,
                              void* d_out, int out_size, void* d_ws, size_t ws_size,
                              hipStream_t stream) {
    const float* x  = (const float*)d_in[0];
    const float* fb = (const float*)d_in[1];
    float* out = (float*)d_out;

    if (ws_size >= WS_NEED) {
        unsigned short* ws = (unsigned short*)d_ws;
        zero_cnt<<<1, 1, 0, stream>>>(ws);
        split_fb<<<(FBT_SLOTS + 255) / 256, 256, 0, stream>>>(fb, ws);
        split_x<<<(64 * (XPLANE / 8) + 255) / 256, 256, 0, stream>>>(x, ws);
        stft_gemm<<<5184, 256, 65536, stream>>>(ws, out);
        stft_axis<<<(BATCH * TWIN * 64 + 255) / 256, 256, 0, stream>>>(x, fb, out);
        stft_fix2<<<1024, 256, 0, stream>>>(x, fb, ws, out);
    } else {
        dim3 grid(8, 9, BATCH);
        stft_gemm_legacy<<<grid, 256, 0, stream>>>(x, fb, out);
        int nwaves = BATCH * TWIN;
        int nblk = (nwaves * 64 + 255) / 256;
        stft_nyq<<<nblk, 256, 0, stream>>>(x, fb, out);
        stft_fix_legacy<<<2048, 256, 0, stream>>>(x, fb, out);
    }
}

// Round 10
// 744.286 us; speedup vs baseline: 1.9687x; 1.1041x over previous
//
#include <hip/hip_runtime.h>
#include <math.h>

#define BATCH 64
#define LSAMP 524288
#define KLEN 1024
#define HOP 512
#define CBIN 513
#define TWIN 1027
#define BCT (64LL * 513 * 1027)   // 33718464

typedef unsigned int uint32;
using short8   = __attribute__((ext_vector_type(8))) short;
using ushort8v = __attribute__((ext_vector_type(8))) unsigned short;
using f32x4    = __attribute__((ext_vector_type(4))) float;

// ---- bf16 hi/lo workspace layout (ushort element offsets) — R4/R5 proven ----
#define FBT_SLOTS (9 * 32 * 512)                  // 147456 slots of 8
#define FBH_OFF 0u
#define FBL_OFF ((uint32)FBT_SLOTS * 8u)          // 1,179,648
#define XPLANE  526336                            // 1024 pad + 524288 + 1024 pad
#define XH_OFF  (2u * (uint32)FBT_SLOTS * 8u)     // 2,359,296
#define XL_OFF  (XH_OFF + 64u * (uint32)XPLANE)   // 36,044,800
#define LIST_OFF_U (XL_OFF + 64u * (uint32)XPLANE) // 69,730,304
#define LIST_CAP  1000000u
#define WS_NEED   ((size_t)(LIST_OFF_U + 8u + 2u * LIST_CAP) * 2)  // 143,460,624 B

__device__ __forceinline__ unsigned short bfh(float v) {
    uint32 u = __float_as_uint(v);
    return (unsigned short)((u + 0x7fffu + ((u >> 16) & 1u)) >> 16);
}
__device__ __forceinline__ float bf2f(unsigned short h) {
    return __uint_as_float(((uint32)h) << 16);
}
__device__ __forceinline__ void gld16(const void* g, void* l) {
    using GT = const __attribute__((address_space(1))) unsigned int;
    using LT = __attribute__((address_space(3))) unsigned int;
    __builtin_amdgcn_global_load_lds((GT*)g, (LT*)l, 16, 0, 0);
}

__global__ void zero_cnt(unsigned short* ws) {
    ((uint32*)(ws + LIST_OFF_U))[0] = 0u;
}

// ---------------- pre-pass: fb -> pre-swizzled bf16 hi/lo tiles (R4 verbatim) ----------------
__global__ __launch_bounds__(256)
void split_fb(const float* __restrict__ fb, unsigned short* __restrict__ ws) {
    int id = blockIdx.x * 256 + threadIdx.x;
    if (id >= FBT_SLOTS) return;
    int slot = id & 511;
    int tile = id >> 9;          // ct*32 + ks
    int ks = tile & 31;
    int ct = tile >> 5;
    int row = slot >> 2;
    int unit = (slot & 3) ^ ((row >> 1) & 3);
    int c0 = (ct < 8) ? ct * 64 : 449;
    int c = (row < 64) ? (c0 + row) : (513 + c0 + (row - 64));
    int k0 = ks * 32 + unit * 8;
    const float4* src = (const float4*)(fb + (size_t)c * KLEN + k0);
    float4 a = src[0], b = src[1];
    float vv[8] = {a.x, a.y, a.z, a.w, b.x, b.y, b.z, b.w};
    ushort8v hh, ll;
#pragma unroll
    for (int j = 0; j < 8; ++j) {
        unsigned short h = bfh(vv[j]);
        hh[j] = h;
        ll[j] = bfh(vv[j] - bf2f(h));
    }
    *(ushort8v*)&ws[FBH_OFF + (size_t)id * 8] = hh;
    *(ushort8v*)&ws[FBL_OFF + (size_t)id * 8] = ll;
}

// ---------------- pre-pass: x -> zero-padded bf16 hi/lo planes (R4 verbatim) ----------------
__global__ __launch_bounds__(256)
void split_x(const float* __restrict__ x, unsigned short* __restrict__ ws) {
    long i = (long)blockIdx.x * 256 + threadIdx.x;
    if (i >= 64L * (XPLANE / 8)) return;
    int b = (int)(i / (XPLANE / 8));
    int j = (int)(i % (XPLANE / 8)) * 8;
    long sample = (long)j - 1024;
    float vv[8] = {0.f,0.f,0.f,0.f,0.f,0.f,0.f,0.f};
    if (sample >= 0 && sample < LSAMP) {
        const float4* s = (const float4*)(x + (size_t)b * LSAMP + sample);
        float4 a = s[0], c = s[1];
        vv[0]=a.x; vv[1]=a.y; vv[2]=a.z; vv[3]=a.w;
        vv[4]=c.x; vv[5]=c.y; vv[6]=c.z; vv[7]=c.w;
    }
    ushort8v hh, ll;
#pragma unroll
    for (int jj = 0; jj < 8; ++jj) {
        unsigned short h = bfh(vv[jj]);
        hh[jj] = h;
        ll[jj] = bfh(vv[jj] - bf2f(h));
    }
    *(ushort8v*)&ws[(size_t)XH_OFF + (size_t)b * XPLANE + j] = hh;
    *(ushort8v*)&ws[(size_t)XL_OFF + (size_t)b * XPLANE + j] = ll;
}

// ---------------- DIAGNOSTIC: R5 skeleton, half staging (AH/XH), single hh MFMA pass ------
// Identical grid/LDS/slot-mapping/barriers to production. Dumps to d_out scratch
// (fully overwritten by production gemm afterwards).
__global__ __launch_bounds__(256, 2)
void stft_diag(const unsigned short* __restrict__ ws, float* __restrict__ out) {
    extern __shared__ unsigned short sm[];

    const int tid  = threadIdx.x;
    const int lane = tid & 63;
    const int w    = tid >> 6;
    const int wm   = w >> 1;
    const int wn   = w & 1;
    const int lm   = lane & 15;
    const int lg   = lane >> 4;
    const uint32 swz = (uint32)((lm >> 1) & 3);

    const int p   = blockIdx.x;
    const int xcd = p & 7;
    const int q   = p >> 3;
    const int ct  = q % 9;
    const int g   = (q / 9) * 8 + xcd;
    const int nt  = g % 9;
    const int b   = g / 9;
    const int n0  = nt * 128;

    f32x4 acc[4][4];
#pragma unroll
    for (int i = 0; i < 4; ++i)
#pragma unroll
        for (int j = 0; j < 4; ++j) acc[i][j] = (f32x4)0.f;

    auto STAGE = [&](int d, int ks) {
        const int s0 = w * 128;
        const uint32 atile = (uint32)(ct * 32 + ks) * 4096u;
#pragma unroll
        for (int r = 0; r < 2; ++r) {
            const int sbase = s0 + r * 64;
            const uint32 slot = (uint32)(sbase + lane);
            const uint32 dsto = (uint32)d * 16384u + (uint32)sbase * 8u;
            gld16(&ws[atile + slot * 8u], &sm[dsto]);                       // AH only
            const uint32 brow  = slot >> 2;
            const uint32 bunit = (slot & 3u) ^ ((brow >> 1) & 3u);
            uint32 pidx = (uint32)(n0 + brow) * 512u + (uint32)ks * 32u + bunit * 8u;
            if (pidx > (uint32)(XPLANE - 8)) pidx = (uint32)(XPLANE - 8);
            gld16(&ws[(size_t)XH_OFF + (size_t)b * XPLANE + pidx], &sm[dsto + 8192u]);  // XH only
        }
    };

    STAGE(0, 0);
    __syncthreads();

    for (int ks = 0; ks < 32; ++ks) {
        const int cur = ks & 1;
        if (ks < 31) STAGE(cur ^ 1, ks + 1);

        const uint32 base = (uint32)cur * 16384u;
        short8 ah[4];
#pragma unroll
        for (int mi = 0; mi < 4; ++mi) {
            const uint32 row = (uint32)(wm * 64 + mi * 16 + lm);
            ah[mi] = *(const short8*)&sm[base + row * 32u + (uint32)((lg ^ swz) * 8)];
        }
#pragma unroll
        for (int ni = 0; ni < 4; ++ni) {
            const uint32 row = (uint32)(wn * 64 + ni * 16 + lm);
            short8 bh = *(const short8*)&sm[base + 8192u + row * 32u + (uint32)((lg ^ swz) * 8)];
#pragma unroll
            for (int mi = 0; mi < 4; ++mi)
                acc[mi][ni] = __builtin_amdgcn_mfma_f32_16x16x32_bf16(ah[mi], bh, acc[mi][ni], 0, 0, 0);
        }
        __syncthreads();
    }

    float tot = 0.f;
#pragma unroll
    for (int mi = 0; mi < 4; ++mi)
#pragma unroll
        for (int ni = 0; ni < 4; ++ni)
#pragma unroll
            for (int r = 0; r < 4; ++r) tot += acc[mi][ni][r];
    out[(size_t)(p & 255) * 256 + tid] = tot;   // scratch; overwritten by production
}

// ---------------- PRODUCTION: R5 gemm verbatim + fused risky-flagging epilogue ----------------
__global__ __launch_bounds__(256, 2)
void stft_gemm(unsigned short* __restrict__ ws, float* __restrict__ out) {
    extern __shared__ unsigned short sm[];

    const int tid  = threadIdx.x;
    const int lane = tid & 63;
    const int w    = tid >> 6;
    const int wm   = w >> 1;
    const int wn   = w & 1;
    const int lm   = lane & 15;
    const int lg   = lane >> 4;
    const uint32 swz = (uint32)((lm >> 1) & 3);

    const int p   = blockIdx.x;
    const int xcd = p & 7;
    const int q   = p >> 3;
    const int ct  = q % 9;
    const int g   = (q / 9) * 8 + xcd;
    const int nt  = g % 9;
    const int b   = g / 9;
    const int c0  = (ct < 8) ? ct * 64 : 449;
    const int n0  = nt * 128;

    f32x4 acc[4][4];
#pragma unroll
    for (int i = 0; i < 4; ++i)
#pragma unroll
        for (int j = 0; j < 4; ++j) acc[i][j] = (f32x4)0.f;

    auto STAGE = [&](int d, int ks) {
        const int s0 = w * 128;
        const uint32 atile = (uint32)(ct * 32 + ks) * 4096u;
#pragma unroll
        for (int r = 0; r < 2; ++r) {
            const int sbase = s0 + r * 64;
            const uint32 slot = (uint32)(sbase + lane);
            const uint32 dsto = (uint32)d * 16384u + (uint32)sbase * 8u;
            gld16(&ws[atile + slot * 8u],           &sm[dsto]);             // AH
            gld16(&ws[FBL_OFF + atile + slot * 8u], &sm[dsto + 4096u]);     // AL
            const uint32 brow  = slot >> 2;
            const uint32 bunit = (slot & 3u) ^ ((brow >> 1) & 3u);
            uint32 pidx = (uint32)(n0 + brow) * 512u + (uint32)ks * 32u + bunit * 8u;
            if (pidx > (uint32)(XPLANE - 8)) pidx = (uint32)(XPLANE - 8);
            gld16(&ws[(size_t)XH_OFF + (size_t)b * XPLANE + pidx], &sm[dsto + 8192u]);   // XH
            gld16(&ws[(size_t)XL_OFF + (size_t)b * XPLANE + pidx], &sm[dsto + 12288u]);  // XL
        }
    };

    STAGE(0, 0);
    __syncthreads();

    for (int ks = 0; ks < 32; ++ks) {
        const int cur = ks & 1;
        if (ks < 31) STAGE(cur ^ 1, ks + 1);

        const uint32 base = (uint32)cur * 16384u;
        short8 ah[4], al[4], bh[4], bl[4];
#pragma unroll
        for (int mi = 0; mi < 4; ++mi) {
            const uint32 row = (uint32)(wm * 64 + mi * 16 + lm);
            const uint32 o = base + row * 32u + (uint32)((lg ^ swz) * 8);
            ah[mi] = *(const short8*)&sm[o];
            al[mi] = *(const short8*)&sm[o + 4096u];
        }
#pragma unroll
        for (int ni = 0; ni < 4; ++ni) {
            const uint32 row = (uint32)(wn * 64 + ni * 16 + lm);
            const uint32 o = base + 8192u + row * 32u + (uint32)((lg ^ swz) * 8);
            bh[ni] = *(const short8*)&sm[o];
            bl[ni] = *(const short8*)&sm[o + 4096u];
        }
#pragma unroll
        for (int mi = 0; mi < 4; ++mi)
#pragma unroll
            for (int ni = 0; ni < 4; ++ni)
                acc[mi][ni] = __builtin_amdgcn_mfma_f32_16x16x32_bf16(ah[mi], bh[ni], acc[mi][ni], 0, 0, 0);
#pragma unroll
        for (int mi = 0; mi < 4; ++mi)
#pragma unroll
            for (int ni = 0; ni < 4; ++ni)
                acc[mi][ni] = __builtin_amdgcn_mfma_f32_16x16x32_bf16(ah[mi], bl[ni], acc[mi][ni], 0, 0, 0);
#pragma unroll
        for (int mi = 0; mi < 4; ++mi)
#pragma unroll
            for (int ni = 0; ni < 4; ++ni)
                acc[mi][ni] = __builtin_amdgcn_mfma_f32_16x16x32_bf16(al[mi], bh[ni], acc[mi][ni], 0, 0, 0);

        __syncthreads();
    }

    // epilogue: exchange re/im (R5 layout), mag+phase, fused risky-flagging
    float* eps = (float*)sm;   // [2][64][132] f32
    uint32* cntr = (uint32*)(ws + LIST_OFF_U);
    uint32* list = cntr + 4;
    const float pi_f = 3.14159265f;

#pragma unroll
    for (int mi = 0; mi < 4; ++mi)
#pragma unroll
        for (int ni = 0; ni < 4; ++ni)
#pragma unroll
            for (int r = 0; r < 4; ++r) {
                int cr = mi * 16 + lg * 4 + r;
                int nc = wn * 64 + ni * 16 + lm;
                eps[wm * 8448 + cr * 132 + nc] = acc[mi][ni][r];
            }
    __syncthreads();
#pragma unroll 4
    for (int qq = 0; qq < 32; ++qq) {
        int id = qq * 256 + tid;
        int cr = id >> 7, nc = id & 127;
        int n = n0 + nc;
        bool risky = false;
        size_t ob = 0;
        if (n < TWIN) {
            float re = eps[cr * 132 + nc];
            float im = eps[8448 + cr * 132 + nc];
            int c = c0 + cr;
            float m  = sqrtf(fmaf(re, re, fmaf(im, im, 1e-10f)));
            float pv = atan2f(im, re);
            ob = ((size_t)b * CBIN + c) * TWIN + n;
            out[ob]       = m;
            out[BCT + ob] = pv;
            bool edge = (n == 0) | (n == 1026);
            bool axis = (c == 0) | (c == 512);
            risky = !edge && ((m < 2e-3f) ||
                              (!axis && (pi_f - fabsf(pv)) * m < 3e-3f));
        }
        unsigned long long mask = __ballot(risky);
        if (mask) {
            int leader = __ffsll(mask) - 1;
            uint32 bslot = 0;
            if (lane == leader) bslot = atomicAdd(cntr, (uint32)__popcll(mask));
            bslot = (uint32)__shfl((int)bslot, leader);
            if (risky) {
                uint32 slot = bslot + (uint32)__popcll(mask & ((1ULL << lane) - 1ULL));
                if (slot < LIST_CAP) list[slot] = (uint32)ob;
            }
        }
    }
}

// ---------------- fp64 recompute over compacted risky list (validated) ----------------
__global__ __launch_bounds__(256)
void stft_fix2(const float* __restrict__ x, const float* __restrict__ fb,
               const unsigned short* __restrict__ ws, float* __restrict__ out) {
    const uint32* cntr = (const uint32*)(ws + LIST_OFF_U);
    const uint32* list = cntr + 4;
    uint32 count = *cntr;
    if (count > LIST_CAP) count = LIST_CAP;
    const int lane = threadIdx.x & 63;
    const uint32 gw = (uint32)((blockIdx.x * 256 + threadIdx.x) >> 6);
    const uint32 nw = gridDim.x * 4;
    for (uint32 i = gw; i < count; i += nw) {
        uint32 idx = list[i];
        uint32 rw = idx / 1027u;
        uint32 t  = idx - rw * 1027u;
        uint32 bb = rw / 513u;
        uint32 c  = rw - bb * 513u;
        const float* xb = x + (size_t)bb * LSAMP;
        const float* fr = fb + (size_t)c * KLEN;
        const float* fi = fb + (size_t)(513 + c) * KLEN;
        const long s = (long)t * HOP - KLEN;
        double re = 0.0, im = 0.0;
#pragma unroll 4
        for (int k = lane; k < KLEN; k += 64) {
            long gg = s + k;
            double xv = (gg >= 0 && gg < LSAMP) ? (double)xb[gg] : 0.0;
            re = fma((double)fr[k], xv, re);
            im = fma((double)fi[k], xv, im);
        }
#pragma unroll
        for (int off = 32; off > 0; off >>= 1) {
            re += __shfl_down(re, off);
            im += __shfl_down(im, off);
        }
        if (lane == 0) {
            out[idx]       = (float)sqrt(re * re + im * im + 1e-10);
            out[BCT + idx] = (float)atan2(im, re);
        }
    }
}

// ================= legacy fallback (verified R3/R5 path, only if ws too small) =================
__global__ __launch_bounds__(256)
void stft_gemm_legacy(const float* __restrict__ x, const float* __restrict__ fb,
                      float* __restrict__ out) {
    __shared__ unsigned short sml[16384];
    unsigned short* AH = sml;
    unsigned short* AL = sml + 4096;
    unsigned short* BH = sml + 8192;
    unsigned short* BL = sml + 12288;

    const int tid  = threadIdx.x;
    const int lane = tid & 63;
    const int w    = tid >> 6;
    const int wm   = w >> 1;
    const int wn   = w & 1;
    const int lm   = lane & 15;
    const int lk   = (lane >> 4) * 8;

    const int ct = blockIdx.x;
    const int nt = blockIdx.y;
    const int b  = blockIdx.z;
    const int c0 = ct * 64;
    const int n0 = nt * 128;

    const float4* fbg = (const float4*)fb;
    const float*  xb  = x + (size_t)b * LSAMP;

    int srow[4], su[4], sfbrow[4];
    long sxbase0[4];
#pragma unroll
    for (int pp = 0; pp < 4; ++pp) {
        int id = pp * 256 + tid;
        int row = id >> 3, u = id & 7;
        srow[pp] = row; su[pp] = u;
        sfbrow[pp] = (row < 64) ? (c0 + row) : (513 + c0 + (row - 64));
        sxbase0[pp] = 512L * (n0 + row) + 4L * u - 1024L;
    }

    f32x4 acc[4][4];
#pragma unroll
    for (int i = 0; i < 4; ++i)
#pragma unroll
        for (int j = 0; j < 4; ++j) acc[i][j] = (f32x4)0.f;

    float4 pa[4], pb[4];
#pragma unroll
    for (int pp = 0; pp < 4; ++pp) {
        pa[pp] = fbg[(size_t)sfbrow[pp] * 256 + su[pp]];
        long base = sxbase0[pp];
        pb[pp] = (base >= 0 && base < LSAMP) ? *(const float4*)(xb + base)
                                             : make_float4(0.f, 0.f, 0.f, 0.f);
    }

    for (int ks = 0; ks < 32; ++ks) {
        __syncthreads();
#pragma unroll
        for (int pp = 0; pp < 4; ++pp) {
            int o = srow[pp] * 32 + su[pp] * 4;
            float4 va = pa[pp], vb = pb[pp];
            ushort4 h, l;
            h.x = bfh(va.x); l.x = bfh(va.x - bf2f(h.x));
            h.y = bfh(va.y); l.y = bfh(va.y - bf2f(h.y));
            h.z = bfh(va.z); l.z = bfh(va.z - bf2f(h.z));
            h.w = bfh(va.w); l.w = bfh(va.w - bf2f(h.w));
            *(ushort4*)&AH[o] = h; *(ushort4*)&AL[o] = l;
            h.x = bfh(vb.x); l.x = bfh(vb.x - bf2f(h.x));
            h.y = bfh(vb.y); l.y = bfh(vb.y - bf2f(h.y));
            h.z = bfh(vb.z); l.z = bfh(vb.z - bf2f(h.z));
            h.w = bfh(vb.w); l.w = bfh(vb.w - bf2f(h.w));
            *(ushort4*)&BH[o] = h; *(ushort4*)&BL[o] = l;
        }
        __syncthreads();

        if (ks < 31) {
            int k0n = (ks + 1) * 32;
#pragma unroll
            for (int pp = 0; pp < 4; ++pp) {
                pa[pp] = fbg[(size_t)sfbrow[pp] * 256 + (k0n >> 2) + su[pp]];
                long base = sxbase0[pp] + k0n;
                pb[pp] = (base >= 0 && base < LSAMP) ? *(const float4*)(xb + base)
                                                     : make_float4(0.f, 0.f, 0.f, 0.f);
            }
        }

        short8 ah[4], al[4], bh[4], bl[4];
#pragma unroll
        for (int mi = 0; mi < 4; ++mi) {
            int o = (wm * 64 + mi * 16 + lm) * 32 + lk;
            ah[mi] = *(const short8*)&AH[o];
            al[mi] = *(const short8*)&AL[o];
        }
#pragma unroll
        for (int ni = 0; ni < 4; ++ni) {
            int o = (wn * 64 + ni * 16 + lm) * 32 + lk;
            bh[ni] = *(const short8*)&BH[o];
            bl[ni] = *(const short8*)&BL[o];
        }
#pragma unroll
        for (int mi = 0; mi < 4; ++mi)
#pragma unroll
            for (int ni = 0; ni < 4; ++ni)
                acc[mi][ni] = __builtin_amdgcn_mfma_f32_16x16x32_bf16(ah[mi], bh[ni], acc[mi][ni], 0, 0, 0);
#pragma unroll
        for (int mi = 0; mi < 4; ++mi)
#pragma unroll
            for (int ni = 0; ni < 4; ++ni)
                acc[mi][ni] = __builtin_amdgcn_mfma_f32_16x16x32_bf16(ah[mi], bl[ni], acc[mi][ni], 0, 0, 0);
#pragma unroll
        for (int mi = 0; mi < 4; ++mi)
#pragma unroll
            for (int ni = 0; ni < 4; ++ni)
                acc[mi][ni] = __builtin_amdgcn_mfma_f32_16x16x32_bf16(al[mi], bh[ni], acc[mi][ni], 0, 0, 0);
    }

    float* epsRe = (float*)sml;
    float* epsIm = (float*)(sml + 8192);
#pragma unroll
    for (int h = 0; h < 2; ++h) {
        __syncthreads();
#pragma unroll
        for (int mi = 0; mi < 4; ++mi)
#pragma unroll
            for (int nj = 0; nj < 2; ++nj) {
                int ni = 2 * h + nj;
#pragma unroll
                for (int r = 0; r < 4; ++r) {
                    int cr   = mi * 16 + (lane >> 4) * 4 + r;
                    int nbuf = wn * 32 + nj * 16 + lm;
                    if (wm == 0) epsRe[cr * 64 + nbuf] = acc[mi][ni][r];
                    else         epsIm[cr * 64 + nbuf] = acc[mi][ni][r];
                }
            }
        __syncthreads();
#pragma unroll
        for (int qq = 0; qq < 16; ++qq) {
            int id   = qq * 256 + tid;
            int cr   = id >> 6;
            int nbuf = id & 63;
            int nr   = (nbuf >> 5) * 64 + h * 32 + (nbuf & 31);
            int n    = n0 + nr;
            if (n < TWIN) {
                float re = epsRe[cr * 64 + nbuf];
                float im = epsIm[cr * 64 + nbuf];
                size_t base = ((size_t)b * CBIN + (c0 + cr)) * TWIN + n;
                out[base]       = sqrtf(fmaf(re, re, fmaf(im, im, 1e-10f)));
                out[BCT + base] = atan2f(im, re);
            }
        }
    }
}

__global__ __launch_bounds__(256)
void stft_nyq(const float* __restrict__ x, const float* __restrict__ fb,
              float* __restrict__ out) {
    const int gw   = (int)((blockIdx.x * 256 + threadIdx.x) >> 6);
    const int lane = threadIdx.x & 63;
    if (gw >= BATCH * TWIN) return;
    const int b = gw / TWIN;
    const int t = gw % TWIN;
    const long s = (long)t * HOP - KLEN;
    const float* xb = x + (size_t)b * LSAMP;
    const float* frow  = fb + (size_t)512 * KLEN;
    const float* firow = fb + (size_t)1025 * KLEN;

    float re = 0.f, im = 0.f;
    for (int k = lane; k < KLEN; k += 64) {
        long gg = s + k;
        float xv = (gg >= 0 && gg < LSAMP) ? xb[gg] : 0.f;
        re = fmaf(xv, frow[k], re);
        im = fmaf(xv, firow[k], im);
    }
#pragma unroll
    for (int off = 32; off > 0; off >>= 1) {
        re += __shfl_down(re, off);
        im += __shfl_down(im, off);
    }
    if (lane == 0) {
        size_t base = ((size_t)b * CBIN + 512) * TWIN + t;
        out[base]       = sqrtf(fmaf(re, re, fmaf(im, im, 1e-10f)));
        out[BCT + base] = atan2f(im, re);
    }
}

__global__ __launch_bounds__(256)
void stft_fix_legacy(const float* __restrict__ x, const float* __restrict__ fb,
                     float* __restrict__ out) {
    const int lane = threadIdx.x & 63;
    const uint32 nquad = (uint32)(BCT / 4);
    const uint32 nquad_pad = (nquad + 63u) & ~63u;
    const uint32 stride = gridDim.x * 256;
    for (uint32 gq = blockIdx.x * 256 + threadIdx.x; gq < nquad_pad; gq += stride) {
        const bool live = gq < nquad;
        float mm[4] = {1e9f, 1e9f, 1e9f, 1e9f};
        float pp[4] = {0.f, 0.f, 0.f, 0.f};
        if (live) {
            float4 mv = *(const float4*)&out[(size_t)gq * 4];
            float4 pv = *(const float4*)&out[BCT + (size_t)gq * 4];
            mm[0]=mv.x; mm[1]=mv.y; mm[2]=mv.z; mm[3]=mv.w;
            pp[0]=pv.x; pp[1]=pv.y; pp[2]=pv.z; pp[3]=pv.w;
        }
        bool cand = false;
#pragma unroll
        for (int j = 0; j < 4; ++j)
            cand |= (mm[j] < 2e-3f) || ((3.14159265f - fabsf(pp[j])) * mm[j] < 3e-3f);
        if (__ballot(cand) == 0ULL) continue;

        bool risky[4] = {false, false, false, false};
        if (live) {
            uint32 i0  = gq * 4u;
            uint32 row = i0 / 1027u;
            uint32 t0  = i0 - row * 1027u;
            uint32 cc0 = row % 513u;
#pragma unroll
            for (int j = 0; j < 4; ++j) {
                uint32 t = t0 + j, c = cc0;
                if (t >= 1027u) { t -= 1027u; c = (c == 512u) ? 0u : c + 1u; }
                bool edge = (t == 0u) | (t == 1026u);
                bool axis = (c == 0u) | (c == 512u);
                risky[j] = !edge && ((mm[j] < 2e-3f) ||
                                     (!axis && (3.14159265f - fabsf(pp[j])) * mm[j] < 3e-3f));
            }
        }
#pragma unroll
        for (int j = 0; j < 4; ++j) {
            unsigned long long mask = __ballot(risky[j]);
            while (mask) {
                int src = __ffsll(mask) - 1;
                mask &= mask - 1;
                uint32 idx = (gq - lane + (uint32)src) * 4u + (uint32)j;
                uint32 rw = idx / 1027u;
                uint32 t  = idx - rw * 1027u;
                uint32 bb = rw / 513u;
                uint32 c  = rw - bb * 513u;
                const float* xb = x + (size_t)bb * LSAMP;
                const float* fr = fb + (size_t)c * KLEN;
                const float* fi = fb + (size_t)(513 + c) * KLEN;
                const long s = (long)t * HOP - KLEN;
                double re = 0.0, im = 0.0;
                for (int k = lane; k < KLEN; k += 64) {
                    long gg = s + k;
                    double xv = (gg >= 0 && gg < LSAMP) ? (double)xb[gg] : 0.0;
                    re = fma((double)fr[k], xv, re);
                    im = fma((double)fi[k], xv, im);
                }
#pragma unroll
                for (int off = 32; off > 0; off >>= 1) {
                    re += __shfl_down(re, off);
                    im += __shfl_down(im, off);
                }
                if (lane == 0) {
                    out[idx]       = (float)sqrt(re * re + im * im + 1e-10);
                    out[BCT + idx] = (float)atan2(im, re);
                }
            }
        }
    }
}

extern "C" void kernel_launch(void* const* d_in, const int* in_sizes, int n_in,
                              void* d_out, int out_size, void* d_ws, size_t ws_size,
                              hipStream_t stream) {
    const float* x  = (const float*)d_in[0];
    const float* fb = (const float*)d_in[1];
    float* out = (float*)d_out;

    if (ws_size >= WS_NEED) {
        unsigned short* ws = (unsigned short*)d_ws;
        zero_cnt<<<1, 1, 0, stream>>>(ws);
        split_fb<<<(FBT_SLOTS + 255) / 256, 256, 0, stream>>>(fb, ws);
        split_x<<<(64 * (XPLANE / 8) + 255) / 256, 256, 0, stream>>>(x, ws);
        stft_diag<<<5184, 256, 67584, stream>>>(ws, out);   // A/B probe; output overwritten below
        stft_gemm<<<5184, 256, 67584, stream>>>(ws, out);
        stft_fix2<<<1024, 256, 0, stream>>>(x, fb, ws, out);
    } else {
        dim3 grid(8, 9, BATCH);
        stft_gemm_legacy<<<grid, 256, 0, stream>>>(x, fb, out);
        int nwaves = BATCH * TWIN;
        int nblk = (nwaves * 64 + 255) / 256;
        stft_nyq<<<nblk, 256, 0, stream>>>(x, fb, out);
        stft_fix_legacy<<<2048, 256, 0, stream>>>(x, fb, out);
    }
}